// Round 8
// baseline (524.255 us; speedup 1.0000x reference)
//
#include <hip/hip_runtime.h>

// GCN layer: out = relu(segment_sum(features[edge_src], edge_dst) @ W + b)
// N=100000, E=1600000, D=F=128.
//
// Round-8 structure (round-7 post-mortem: gather is NOT byte-bound; the
// per-entry LDS b128 RMW (~24 cyc/entry of LDS pipe) is the bottleneck):
//  1) fill: chunk-private binning by bucket=dst>>6 into chunk-MAJOR 64B
//     cells (block c stores within a contiguous 100KB region). LDS counters,
//     no global atomics hot-path; rare overflow -> global list.
//  2) fused: wave w (of 4) owns rows dl&3==w and accumulates them in
//     REGISTERS (16 x float2/lane). Sweep cells, ballot my-class entries,
//     extract via scalar ffs+readlane (wave-uniform row per entry -> scalar
//     switch into fixed regs), 4-deep pipelined row gathers. ZERO LDS in
//     the gather loop. One hl write per row at the end, then fp32 GEMM.

constexpr int D     = 128;   // input feature dim
constexpr int F     = 128;   // output feature dim
constexpr int NCH   = 192;   // edge chunks (= fill grid)
constexpr int CAPC  = 16;    // cell capacity = one 64B line (lambda ~5.33)
constexpr int NBMAX = 2048;  // max buckets (N < 2^17)
constexpr int OVCAP = 16384; // overflow list capacity

// ---------------------------------------------------------------------------
// Kernel 1: chunk-private binning. entry = src | (dl<<17) (N < 2^17).
// Slot layout chunk-major: cell (c, bucket) at gslot[(c*NB + bucket)*CAPC].
// ---------------------------------------------------------------------------
__global__ __launch_bounds__(1024) void fill_kernel(
    const int* __restrict__ src,
    const int* __restrict__ dst,
    int* __restrict__ gcnt,
    int* __restrict__ gslot,
    int* __restrict__ ovf_cnt,
    int2* __restrict__ ovf,
    int E, int NB, int CH) {
  __shared__ int lcnt[NBMAX];
  int c = blockIdx.x;
  int tid = threadIdx.x;

  for (int i = tid; i < NB; i += 1024) lcnt[i] = 0;
  __syncthreads();

  int e0 = c * CH;
  int e1 = min(E, e0 + CH);
  size_t cbase = (size_t)c * NB * CAPC;
  for (int e = e0 + tid; e < e1; e += 1024) {
    int t = dst[e];
    int s = src[e];
    int bucket = t >> 6;
    int entry = s | ((t & 63) << 17);
    int pos = atomicAdd(&lcnt[bucket], 1);      // LDS int atomic
    if (pos < CAPC) {
      gslot[cbase + (size_t)bucket * CAPC + pos] = entry;
    } else {
      int gp = atomicAdd(ovf_cnt, 1);           // rare (~10 expected total)
      if (gp < OVCAP) ovf[gp] = make_int2(entry, bucket);
    }
  }
  __syncthreads();

  for (int i = tid; i < NB; i += 1024)
    gcnt[(size_t)c * NB + i] = lcnt[i];
}

// ---------------------------------------------------------------------------
// Kernel 2 (fused): register-accumulated gather -> GEMM+bias+relu.
// ---------------------------------------------------------------------------
__global__ __launch_bounds__(256) void fused_kernel(
    const float* __restrict__ feat,
    const int* __restrict__ gcnt,
    const int* __restrict__ gslot,
    const int* __restrict__ ovf_cnt,
    const int2* __restrict__ ovf,
    const float* __restrict__ W,
    const float* __restrict__ b,
    float* __restrict__ out,
    int N, int NB) {
  __shared__ float hl[64 * D];        // 32 KB aggregated tile
  __shared__ int ccnt[NCH];

  int bb = blockIdx.x;
  int tid = threadIdx.x;
  int w = tid >> 6;                   // wave 0..3 = row class (dl&3)
  int lane = tid & 63;

  if (tid < NCH) ccnt[tid] = min(gcnt[(size_t)tid * NB + bb], CAPC);
  __syncthreads();

  // 16 row accumulators in registers; lane owns floats {2*lane, 2*lane+1}.
  float2 acc[16];
#pragma unroll
  for (int r = 0; r < 16; ++r) acc[r] = make_float2(0.f, 0.f);

  const float2* feat2 = (const float2*)feat;

  auto addrow = [&](int e, float2 v) {
    int r = (e >> 19) & 15;           // dl>>2 (dl&3 == w by selection)
    switch (r) {
      case 0:  acc[0].x  += v.x; acc[0].y  += v.y; break;
      case 1:  acc[1].x  += v.x; acc[1].y  += v.y; break;
      case 2:  acc[2].x  += v.x; acc[2].y  += v.y; break;
      case 3:  acc[3].x  += v.x; acc[3].y  += v.y; break;
      case 4:  acc[4].x  += v.x; acc[4].y  += v.y; break;
      case 5:  acc[5].x  += v.x; acc[5].y  += v.y; break;
      case 6:  acc[6].x  += v.x; acc[6].y  += v.y; break;
      case 7:  acc[7].x  += v.x; acc[7].y  += v.y; break;
      case 8:  acc[8].x  += v.x; acc[8].y  += v.y; break;
      case 9:  acc[9].x  += v.x; acc[9].y  += v.y; break;
      case 10: acc[10].x += v.x; acc[10].y += v.y; break;
      case 11: acc[11].x += v.x; acc[11].y += v.y; break;
      case 12: acc[12].x += v.x; acc[12].y += v.y; break;
      case 13: acc[13].x += v.x; acc[13].y += v.y; break;
      case 14: acc[14].x += v.x; acc[14].y += v.y; break;
      case 15: acc[15].x += v.x; acc[15].y += v.y; break;
    }
  };

  // ---- Sweep all cells (each wave sweeps everything, picks its class) ----
  {
    int i = lane;
    int entry = gslot[((size_t)(i >> 4) * NB + bb) * CAPC + (i & 15)];
    for (int i0 = 0; i0 < NCH * CAPC; i0 += 64) {
      int inx = i0 + 64 + lane;
      int entry_next = 0;
      if (inx < NCH * CAPC)
        entry_next = gslot[((size_t)(inx >> 4) * NB + bb) * CAPC + (inx & 15)];

      int ii = i0 + lane;
      bool mine = ((ii & 15) < ccnt[ii >> 4]) && (((entry >> 17) & 3) == w);
      unsigned long long m = __ballot(mine);

      while (m) {
        int e0, e1 = -1, e2 = -1, e3 = -1;
        {
          unsigned lx = (unsigned)__ffsll(m) - 1;
          e0 = __builtin_amdgcn_readlane(entry, lx);
          m &= m - 1;
        }
        if (m) {
          unsigned lx = (unsigned)__ffsll(m) - 1;
          e1 = __builtin_amdgcn_readlane(entry, lx);
          m &= m - 1;
        }
        if (m) {
          unsigned lx = (unsigned)__ffsll(m) - 1;
          e2 = __builtin_amdgcn_readlane(entry, lx);
          m &= m - 1;
        }
        if (m) {
          unsigned lx = (unsigned)__ffsll(m) - 1;
          e3 = __builtin_amdgcn_readlane(entry, lx);
          m &= m - 1;
        }
        // up to 4 independent 512B row gathers in flight
        float2 v0 = feat2[(size_t)(e0 & 0x1FFFF) * 64 + lane];
        float2 v1 = make_float2(0.f, 0.f);
        float2 v2 = make_float2(0.f, 0.f);
        float2 v3 = make_float2(0.f, 0.f);
        if (e1 >= 0) v1 = feat2[(size_t)(e1 & 0x1FFFF) * 64 + lane];
        if (e2 >= 0) v2 = feat2[(size_t)(e2 & 0x1FFFF) * 64 + lane];
        if (e3 >= 0) v3 = feat2[(size_t)(e3 & 0x1FFFF) * 64 + lane];
        addrow(e0, v0);
        if (e1 >= 0) addrow(e1, v1);
        if (e2 >= 0) addrow(e2, v2);
        if (e3 >= 0) addrow(e3, v3);
      }
      entry = entry_next;
    }
  }

  // ---- Overflow replay (expected ~10 entries globally) ----
  {
    int nov = min(*ovf_cnt, OVCAP);
    for (int i = 0; i < nov; ++i) {
      int2 oe = ovf[i];
      if (oe.y == bb && ((oe.x >> 17) & 3) == w) {
        float2 v = feat2[(size_t)(oe.x & 0x1FFFF) * 64 + lane];
        addrow(oe.x, v);
      }
    }
  }

  // ---- Dump accumulators: row dl = 4*r + w ----
#pragma unroll
  for (int r = 0; r < 16; ++r)
    *(float2*)&hl[(4 * r + w) * D + 2 * lane] = acc[r];
  __syncthreads();

  // ---- GEMM: out[64 x F] = relu(hl @ W + b) ----
  int cg = tid & 31;
  int rg = tid >> 5;
  int row0 = bb * 64;

  const float4* W4 = (const float4*)W;
  const float4* hl4 = (const float4*)hl;

  float4 bv = ((const float4*)b)[cg];
  float gacc[8][4];
#pragma unroll
  for (int r = 0; r < 8; ++r) {
    gacc[r][0] = bv.x; gacc[r][1] = bv.y; gacc[r][2] = bv.z; gacc[r][3] = bv.w;
  }

#pragma unroll 2
  for (int d4 = 0; d4 < D / 4; ++d4) {
    float4 w0 = W4[(size_t)(4 * d4 + 0) * (F / 4) + cg];
    float4 w1 = W4[(size_t)(4 * d4 + 1) * (F / 4) + cg];
    float4 w2 = W4[(size_t)(4 * d4 + 2) * (F / 4) + cg];
    float4 w3 = W4[(size_t)(4 * d4 + 3) * (F / 4) + cg];
#pragma unroll
    for (int r = 0; r < 8; ++r) {
      float4 hv = hl4[(rg + 8 * r) * 32 + d4];
      gacc[r][0] += hv.x * w0.x + hv.y * w1.x + hv.z * w2.x + hv.w * w3.x;
      gacc[r][1] += hv.x * w0.y + hv.y * w1.y + hv.z * w2.y + hv.w * w3.y;
      gacc[r][2] += hv.x * w0.z + hv.y * w1.z + hv.z * w2.z + hv.w * w3.z;
      gacc[r][3] += hv.x * w0.w + hv.y * w1.w + hv.z * w2.w + hv.w * w3.w;
    }
  }

#pragma unroll
  for (int r = 0; r < 8; ++r) {
    int row = row0 + rg + 8 * r;
    if (row < N) {
      float4 o;
      o.x = fmaxf(gacc[r][0], 0.f);
      o.y = fmaxf(gacc[r][1], 0.f);
      o.z = fmaxf(gacc[r][2], 0.f);
      o.w = fmaxf(gacc[r][3], 0.f);
      ((float4*)out)[(size_t)row * (F / 4) + cg] = o;
    }
  }
}

// ---------------------------------------------------------------------------
extern "C" void kernel_launch(void* const* d_in, const int* in_sizes, int n_in,
                              void* d_out, int out_size, void* d_ws, size_t ws_size,
                              hipStream_t stream) {
  const float* feat = (const float*)d_in[0];   // [N, D]
  const float* W    = (const float*)d_in[1];   // [D, F]
  const float* b    = (const float*)d_in[2];   // [F]
  const int* src    = (const int*)d_in[3];     // [E]
  const int* dst    = (const int*)d_in[4];     // [E]

  int N = in_sizes[0] / D;
  int E = in_sizes[3];

  int NB = (N + 63) / 64;                      // buckets / dst-blocks (1563)
  int CH = (E + NCH - 1) / NCH;                // edges per chunk (8334)

  // Workspace layout (ws >= 51.2MB known from round 1):
  //   gcnt    [NCH*NB ints]        @ 0        (~1.2MB)
  //   ovf_cnt [1 int]              @ 2MB
  //   ovf     [OVCAP int2]         @ 2MB+256  (128KB)
  //   gslot   [NCH*NB*CAPC ints]   @ 4MB      (19.2MB, chunk-major 64B cells)
  // Total ~23.2MB.
  int* gcnt     = (int*)d_ws;
  int* ovf_cnt  = (int*)((char*)d_ws + (2u << 20));
  int2* ovf     = (int2*)((char*)d_ws + (2u << 20) + 256);
  int* gslot    = (int*)((char*)d_ws + (4u << 20));

  float* out = (float*)d_out;

  hipMemsetAsync(ovf_cnt, 0, sizeof(int), stream);

  fill_kernel<<<NCH, 1024, 0, stream>>>(src, dst, gcnt, gslot, ovf_cnt, ovf,
                                        E, NB, CH);

  fused_kernel<<<NB, 256, 0, stream>>>(feat, gcnt, gslot, ovf_cnt, ovf,
                                       W, b, out, N, NB);
}